// Round 1
// baseline (806.671 us; speedup 1.0000x reference)
//
#include <hip/hip_runtime.h>
#include <hip/hip_bf16.h>

#define B_ 8
#define T_ 2048
#define C_ 1024
#define S_ 1024      // top_k == reduced sequence length
#define H_ 16
#define DH_ 64
#define DFF_ 4096
#define M_ (B_*S_)   // 8192 rows through the block
#define CHUNKB 2     // batches per attention chunk (scores buffer = 64MB)

typedef __attribute__((ext_vector_type(8))) short bf16x8;
typedef __attribute__((ext_vector_type(4))) float f32x4;

__device__ __forceinline__ short f2bf(float f) {
  __hip_bfloat16 h = __float2bfloat16(f);
  return *reinterpret_cast<short*>(&h);
}
__device__ __forceinline__ float bf2f(short s) {
  __hip_bfloat16 h = *reinterpret_cast<__hip_bfloat16*>(&s);
  return __bfloat162float(h);
}

typedef const __attribute__((address_space(1))) unsigned int* gas_p;
typedef __attribute__((address_space(3))) unsigned int* las_p;
__device__ __forceinline__ void gload_lds16(const void* g, void* l) {
  __builtin_amdgcn_global_load_lds((gas_p)g, (las_p)l, 16, 0, 0);
}

// ---------------- router logits: one wave per token ----------------
__global__ __launch_bounds__(256) void k_router(const float* __restrict__ x,
    const float* __restrict__ wr, float* __restrict__ logits) {
  int tok = blockIdx.x * 4 + (threadIdx.x >> 6);
  int l = threadIdx.x & 63;
  const float* xr = x + (size_t)tok * C_;
  float s = 0.f;
  #pragma unroll
  for (int j = 0; j < C_/64; ++j) s += xr[l + 64*j] * wr[l + 64*j];
  #pragma unroll
  for (int m = 32; m; m >>= 1) s += __shfl_xor(s, m);
  if (l == 0) logits[tok] = s;
}

// ------------- exact top-k via bitonic sort (1 block / batch) -------------
// key1 = (~sortable(val) << 32) | idx  -> ascending sort == value-desc, idx-asc
__global__ __launch_bounds__(1024) void k_topk(const float* __restrict__ logits,
    int* __restrict__ idx, float* __restrict__ wts) {
  __shared__ unsigned long long key[2048];
  int b = blockIdx.x, t = threadIdx.x;
  for (int i = t; i < T_; i += 1024) {
    float v = logits[(size_t)b*T_ + i];
    unsigned u = __float_as_uint(v);
    unsigned so = u ^ ((u >> 31) ? 0xFFFFFFFFu : 0x80000000u);
    key[i] = ((unsigned long long)(~so) << 32) | (unsigned)i;
  }
  __syncthreads();
  for (int k = 2; k <= 2048; k <<= 1) {
    for (int j = k >> 1; j > 0; j >>= 1) {
      int i = ((t & ~(j-1)) << 1) | (t & (j-1));
      int ix = i | j;
      unsigned long long a = key[i], c = key[ix];
      bool up = ((i & k) == 0);
      if ((a > c) == up) { key[i] = c; key[ix] = a; }
      __syncthreads();
    }
  }
  // first 1024 = the top-k; re-key by index and sort ascending
  unsigned long long a = key[t];
  __syncthreads();
  unsigned i0 = (unsigned)(a & 0xFFFFFFFFu);
  unsigned so = ~(unsigned)(a >> 32);
  unsigned bits = (so & 0x80000000u) ? (so ^ 0x80000000u) : ~so; // inverse sortable
  key[t] = ((unsigned long long)i0 << 32) | bits;
  __syncthreads();
  for (int k = 2; k <= 1024; k <<= 1) {
    for (int j = k >> 1; j > 0; j >>= 1) {
      if (t < 512) {
        int i = ((t & ~(j-1)) << 1) | (t & (j-1));
        int ix = i | j;
        unsigned long long a2 = key[i], c2 = key[ix];
        bool up = ((i & k) == 0);
        if ((a2 > c2) == up) { key[i] = c2; key[ix] = a2; }
      }
      __syncthreads();
    }
  }
  idx[(size_t)b*S_ + t] = (int)(key[t] >> 32);
  wts[(size_t)b*S_ + t] = __uint_as_float((unsigned)(key[t] & 0xFFFFFFFFu));
}

// -------- fp32 -> bf16 conversion (weights) --------
__global__ __launch_bounds__(256) void k_cvt(const float* __restrict__ s,
    short* __restrict__ d, int n4) {
  int i = blockIdx.x * 256 + threadIdx.x;
  if (i >= n4) return;
  float4 v = ((const float4*)s)[i];
  short4 o;
  o.x = f2bf(v.x); o.y = f2bf(v.y); o.z = f2bf(v.z); o.w = f2bf(v.w);
  ((short4*)d)[i] = o;
}

// -------- LayerNorm (optionally gathering tokens from x via idx) --------
template<bool GATHER>
__global__ __launch_bounds__(256) void k_ln(const float* __restrict__ x,
    const int* __restrict__ idx, float* __restrict__ hbuf,
    short* __restrict__ obf, const float* __restrict__ g,
    const float* __restrict__ beta) {
  __shared__ float red[8];
  int row = blockIdx.x;
  const float* src;
  if (GATHER) {
    int b = row >> 10, k = row & 1023;
    src = x + ((size_t)b*T_ + idx[b*S_ + k]) * C_;
  } else {
    src = hbuf + (size_t)row * C_;
  }
  int t = threadIdx.x;
  float4 v = *(const float4*)(src + t*4);
  float s  = v.x + v.y + v.z + v.w;
  float s2 = v.x*v.x + v.y*v.y + v.z*v.z + v.w*v.w;
  #pragma unroll
  for (int m = 32; m; m >>= 1) { s += __shfl_xor(s, m); s2 += __shfl_xor(s2, m); }
  int w = t >> 6, lane = t & 63;
  if (lane == 0) { red[w] = s; red[w+4] = s2; }
  __syncthreads();
  s  = red[0]+red[1]+red[2]+red[3];
  s2 = red[4]+red[5]+red[6]+red[7];
  float mu = s * (1.f/(float)C_);
  float var = s2 * (1.f/(float)C_) - mu*mu;
  float rs = rsqrtf(var + 1e-5f);
  int c0 = t*4;
  float4 gw = *(const float4*)(g + c0);
  float4 bw = *(const float4*)(beta + c0);
  short4 o;
  o.x = f2bf((v.x-mu)*rs*gw.x + bw.x);
  o.y = f2bf((v.y-mu)*rs*gw.y + bw.y);
  o.z = f2bf((v.z-mu)*rs*gw.z + bw.z);
  o.w = f2bf((v.w-mu)*rs*gw.w + bw.w);
  *(short4*)(obf + (size_t)row*C_ + c0) = o;
  if (GATHER) *(float4*)(hbuf + (size_t)row*C_ + c0) = v;  // residual stream
}

// -------- generic bf16 GEMM: C = A[M,K] @ B[N,K]^T (m97-style 128-tile) --------
#define EPI_BF16 0
#define EPI_GELU 1
#define EPI_ADD32 2

template<int BM, int BN, int EPI, bool SKIPUP, bool CAUSK>
__global__ __launch_bounds__(256) void k_gemm(
    const short* __restrict__ A, int lda,
    const short* __restrict__ Bp, int ldb,
    void* __restrict__ Cp, int ldc,
    const float* __restrict__ bias,
    int N, int Ktot, int zdiv,
    long long azo, long long azi, long long bzo, long long bzi,
    long long czo, long long czi) {
  __shared__ short As[BM*32];
  __shared__ short Bs[BN*32];
  int z = blockIdx.z;
  int zo = z / zdiv, zi = z % zdiv;
  const short* Ab = A + zo*azo + zi*azi;
  const short* Bb = Bp + zo*bzo + zi*bzi;
  long long coff = zo*czo + zi*czi;
  int nt = N / BN;
  int bm = blockIdx.x / nt, bn = blockIdx.x % nt;
  if (SKIPUP && bn*BN > bm*BM + (BM-1)) return;   // tile fully above diagonal
  int kend = CAUSK ? (bm*BM + BM < Ktot ? bm*BM + BM : Ktot) : Ktot;
  const short* Ar = Ab + (size_t)bm*BM*lda;
  const short* Br = Bb + (size_t)bn*BN*ldb;
  constexpr int WM = BM/2, WN = BN/2, FM = WM/16, FN = WN/16;
  int t = threadIdx.x, lane = t & 63, w = t >> 6;
  int wm = w >> 1, wn = w & 1;
  int lr = lane & 15, lk = (lane >> 4) << 3;
  f32x4 acc[FM][FN] = {};
  for (int k0 = 0; k0 < kend; k0 += 32) {
    #pragma unroll
    for (int c = 0; c < BM/64; ++c) {
      int e = (c*256 + t)*8;
      gload_lds16(Ar + (size_t)(e >> 5)*lda + (k0 + (e & 31)), &As[e]);
    }
    #pragma unroll
    for (int c = 0; c < BN/64; ++c) {
      int e = (c*256 + t)*8;
      gload_lds16(Br + (size_t)(e >> 5)*ldb + (k0 + (e & 31)), &Bs[e]);
    }
    asm volatile("s_waitcnt vmcnt(0)" ::: "memory");
    __syncthreads();
    bf16x8 af[FM], bfv[FN];
    #pragma unroll
    for (int i = 0; i < FM; ++i)
      af[i] = *(const bf16x8*)&As[(wm*WM + i*16 + lr)*32 + lk];
    #pragma unroll
    for (int j = 0; j < FN; ++j)
      bfv[j] = *(const bf16x8*)&Bs[(wn*WN + j*16 + lr)*32 + lk];
    #pragma unroll
    for (int i = 0; i < FM; ++i)
      #pragma unroll
      for (int j = 0; j < FN; ++j)
        acc[i][j] = __builtin_amdgcn_mfma_f32_16x16x32_bf16(af[i], bfv[j], acc[i][j], 0, 0, 0);
    __syncthreads();
  }
  // epilogue: C/D layout col=lane&15, row=(lane>>4)*4+reg  [m89-verified]
  int row0 = bm*BM + wm*WM + ((lane >> 4) << 2);
  int col0 = bn*BN + wn*WN + lr;
  #pragma unroll
  for (int i = 0; i < FM; ++i) {
    #pragma unroll
    for (int j = 0; j < FN; ++j) {
      int col = col0 + j*16;
      float bv = bias ? bias[col] : 0.f;
      #pragma unroll
      for (int r = 0; r < 4; ++r) {
        int row = row0 + i*16 + r;
        float v = acc[i][j][r] + bv;
        if (EPI == EPI_ADD32) {
          float* Co = (float*)Cp + coff;
          Co[(size_t)row*ldc + col] += v;
        } else {
          if (EPI == EPI_GELU) v = 0.5f*v*(1.f + erff(v*0.70710678118654752f));
          short* Co = (short*)Cp + coff;
          Co[(size_t)row*ldc + col] = f2bf(v);
        }
      }
    }
  }
}

// -------- V transpose: qkv[b,s,2C+h*64+d] -> vt[(b*H+h)*64+d][s] --------
__global__ __launch_bounds__(256) void k_vt(const short* __restrict__ qkv,
                                            short* __restrict__ vt) {
  __shared__ short tile[64][65];
  int blk = blockIdx.x;
  int s0 = (blk & 15) << 6;
  int bh = blk >> 4;
  int b = bh >> 4, h = bh & 15;
  const short* src = qkv + (size_t)b*S_*3*C_ + 2*C_ + h*DH_;
  int t = threadIdx.x;
  #pragma unroll
  for (int it = 0; it < 16; ++it) {
    int e = it*256 + t;
    int r = e >> 6, d = e & 63;
    tile[d][r] = src[(size_t)(s0 + r)*3*C_ + d];
  }
  __syncthreads();
  short* dst = vt + (size_t)bh*DH_*S_ + s0;
  #pragma unroll
  for (int it = 0; it < 16; ++it) {
    int e = it*256 + t;
    int d2 = e >> 6, c = e & 63;
    dst[(size_t)d2*S_ + c] = tile[d2][c];
  }
}

// -------- causal softmax, one block per row, row held in registers --------
__global__ __launch_bounds__(256) void k_softmax(short* __restrict__ sc) {
  __shared__ float red[4];
  int rowg = blockIdx.x;
  int q = rowg & (S_-1);
  short* p = sc + (size_t)rowg * S_;
  int t = threadIdx.x;
  float v[4];
  float mx = -3.0e38f;
  #pragma unroll
  for (int i = 0; i < 4; ++i) {
    int c = t + i*256;
    float s = bf2f(p[c]) * 0.125f;           // /sqrt(64)
    v[i] = (c <= q) ? s : -3.0e38f;
    mx = fmaxf(mx, v[i]);
  }
  #pragma unroll
  for (int m = 32; m; m >>= 1) mx = fmaxf(mx, __shfl_xor(mx, m));
  int w = t >> 6, lane = t & 63;
  if (lane == 0) red[w] = mx;
  __syncthreads();
  mx = fmaxf(fmaxf(red[0], red[1]), fmaxf(red[2], red[3]));
  __syncthreads();
  float sum = 0.f;
  #pragma unroll
  for (int i = 0; i < 4; ++i) {
    v[i] = (v[i] > -1.0e38f) ? expf(v[i] - mx) : 0.f;
    sum += v[i];
  }
  #pragma unroll
  for (int m = 32; m; m >>= 1) sum += __shfl_xor(sum, m);
  if (lane == 0) red[w] = sum;
  __syncthreads();
  sum = red[0] + red[1] + red[2] + red[3];
  float inv = 1.f / sum;
  #pragma unroll
  for (int i = 0; i < 4; ++i) p[t + i*256] = f2bf(v[i] * inv);
}

// -------- out = x everywhere --------
__global__ void k_copy(const float* __restrict__ src, float* __restrict__ dst,
                       size_t n4) {
  size_t i = (size_t)blockIdx.x*256 + threadIdx.x;
  size_t stride = (size_t)gridDim.x*256;
  for (; i < n4; i += stride) ((float4*)dst)[i] = ((const float4*)src)[i];
}

// -------- out[selected row] = x + weight * h  (indices unique per batch) --------
__global__ __launch_bounds__(256) void k_scatter(const float* __restrict__ x,
    const int* __restrict__ idx, const float* __restrict__ wts,
    const float* __restrict__ hbuf, float* __restrict__ out) {
  int row = blockIdx.x;
  int b = row >> 10, k = row & 1023;
  int tk = idx[(size_t)b*S_ + k];
  float wv = wts[(size_t)b*S_ + k];
  size_t o  = ((size_t)b*T_ + tk)*C_ + threadIdx.x*4;
  size_t hs = (size_t)row*C_ + threadIdx.x*4;
  float4 xv = *(const float4*)(x + o);
  float4 hv = *(const float4*)(hbuf + hs);
  xv.x += wv*hv.x; xv.y += wv*hv.y; xv.z += wv*hv.z; xv.w += wv*hv.w;
  *(float4*)(out + o) = xv;
}

extern "C" void kernel_launch(void* const* d_in, const int* in_sizes, int n_in,
                              void* d_out, int out_size, void* d_ws, size_t ws_size,
                              hipStream_t stream) {
  const float* x     = (const float*)d_in[0];
  const float* wrt   = (const float*)d_in[1];
  const float* ln1w  = (const float*)d_in[2];
  const float* ln1b  = (const float*)d_in[3];
  const float* wqkv  = (const float*)d_in[4];
  const float* bqkv  = (const float*)d_in[5];
  const float* wo    = (const float*)d_in[6];
  const float* bo    = (const float*)d_in[7];
  const float* ln2w  = (const float*)d_in[8];
  const float* ln2b  = (const float*)d_in[9];
  const float* wfc   = (const float*)d_in[10];
  const float* bfc   = (const float*)d_in[11];
  const float* wproj = (const float*)d_in[12];
  const float* bproj = (const float*)d_in[13];
  float* out = (float*)d_out;

  char* p = (char*)d_ws;
  auto alloc = [&](size_t bytes) {
    char* r = p; p += (bytes + 255) & ~(size_t)255; return r;
  };
  float* logits = (float*)alloc((size_t)B_*T_*4);
  int*   idx    = (int*)  alloc((size_t)B_*S_*4);
  float* wts    = (float*)alloc((size_t)B_*S_*4);
  float* hbuf   = (float*)alloc((size_t)M_*C_*4);
  short* abuf   = (short*)alloc((size_t)M_*C_*2);
  short* qkvb   = (short*)alloc((size_t)M_*3*C_*2);
  short* vtb    = (short*)alloc((size_t)B_*H_*DH_*S_*2);
  short* attnb  = (short*)alloc((size_t)M_*C_*2);
  short* fcb    = (short*)alloc((size_t)M_*DFF_*2);   // also overlaid as scores buf
  short* wqkvb  = (short*)alloc((size_t)3*C_*C_*2);
  short* wob    = (short*)alloc((size_t)C_*C_*2);
  short* wfcb   = (short*)alloc((size_t)DFF_*C_*2);
  short* wprojb = (short*)alloc((size_t)C_*DFF_*2);
  short* scb = fcb;  // scores (CHUNKB*H*S*S bf16 = 64MB) overlays fc buffer
  if (ws_size < (size_t)(p - (char*)d_ws)) return;  // ws too small: loud fail

  // weight conversions to bf16
  k_cvt<<<dim3(3*C_*C_/4/256), dim3(256), 0, stream>>>(wqkv, wqkvb, 3*C_*C_/4);
  k_cvt<<<dim3(C_*C_/4/256),   dim3(256), 0, stream>>>(wo, wob, C_*C_/4);
  k_cvt<<<dim3(DFF_*C_/4/256), dim3(256), 0, stream>>>(wfc, wfcb, DFF_*C_/4);
  k_cvt<<<dim3(C_*DFF_/4/256), dim3(256), 0, stream>>>(wproj, wprojb, C_*DFF_/4);

  // router + exact top-k
  k_router<<<dim3(B_*T_/4), dim3(256), 0, stream>>>(x, wrt, logits);
  k_topk<<<dim3(B_), dim3(1024), 0, stream>>>(logits, idx, wts);

  // gather + LN1 (hbuf = gathered residual, abuf = LN1 out bf16)
  k_ln<true><<<dim3(M_), dim3(256), 0, stream>>>(x, idx, hbuf, abuf, ln1w, ln1b);

  // QKV: [8192,1024] @ [3072,1024]^T -> qkvb bf16
  k_gemm<128,128,EPI_BF16,false,false>
    <<<dim3((M_/128)*(3*C_/128), 1, 1), dim3(256), 0, stream>>>(
      abuf, C_, wqkvb, C_, qkvb, 3*C_, bqkv, 3*C_, C_, 1, 0,0,0,0,0,0);

  // V transpose for PV gemm_bt
  k_vt<<<dim3(B_*H_*(S_/64)), dim3(256), 0, stream>>>(qkvb, vtb);

  // attention, chunks of CHUNKB batches
  for (int b0 = 0; b0 < B_; b0 += CHUNKB) {
    // scores = Q @ K^T (skip fully-masked tiles); scale+mask applied in softmax
    k_gemm<128,128,EPI_BF16,true,false>
      <<<dim3((S_/128)*(S_/128), 1, CHUNKB*H_), dim3(256), 0, stream>>>(
        qkvb + (size_t)b0*S_*3*C_, 3*C_,
        qkvb + (size_t)b0*S_*3*C_ + C_, 3*C_,
        scb, S_, nullptr, S_, DH_, H_,
        (long long)S_*3*C_, (long long)DH_,
        (long long)S_*3*C_, (long long)DH_,
        (long long)H_*S_*S_, (long long)S_*S_);
    k_softmax<<<dim3(CHUNKB*H_*S_), dim3(256), 0, stream>>>(scb);
    // attn = P @ V  (causal K truncation)
    k_gemm<128,64,EPI_BF16,false,true>
      <<<dim3((S_/128)*(DH_/64), 1, CHUNKB*H_), dim3(256), 0, stream>>>(
        scb, S_,
        vtb + (size_t)b0*H_*DH_*S_, S_,
        attnb + (size_t)b0*S_*C_, C_, nullptr, DH_, S_, H_,
        (long long)H_*S_*S_, (long long)S_*S_,
        (long long)H_*DH_*S_, (long long)DH_*S_,
        (long long)S_*C_, (long long)DH_);
  }

  // h += attn @ w_o^T + b_o   (fp32 accumulate into residual)
  k_gemm<128,128,EPI_ADD32,false,false>
    <<<dim3((M_/128)*(C_/128), 1, 1), dim3(256), 0, stream>>>(
      attnb, C_, wob, C_, hbuf, C_, bo, C_, C_, 1, 0,0,0,0,0,0);

  // LN2 -> abuf (bf16 m)
  k_ln<false><<<dim3(M_), dim3(256), 0, stream>>>(nullptr, nullptr, hbuf, abuf, ln2w, ln2b);

  // fc = gelu(m @ w_fc^T + b_fc) bf16   (overwrites the scores overlay — attn done)
  k_gemm<128,128,EPI_GELU,false,false>
    <<<dim3((M_/128)*(DFF_/128), 1, 1), dim3(256), 0, stream>>>(
      abuf, C_, wfcb, C_, fcb, DFF_, bfc, DFF_, C_, 1, 0,0,0,0,0,0);

  // h += fc @ w_proj^T + b_proj
  k_gemm<128,128,EPI_ADD32,false,false>
    <<<dim3((M_/128)*(C_/128), 1, 1), dim3(256), 0, stream>>>(
      fcb, DFF_, wprojb, DFF_, hbuf, C_, bproj, C_, DFF_, 1, 0,0,0,0,0,0);

  // combine: out = x; out[idx] = x + w*h
  k_copy<<<dim3(2048), dim3(256), 0, stream>>>(x, out, (size_t)B_*T_*C_/4);
  k_scatter<<<dim3(M_), dim3(256), 0, stream>>>(x, idx, wts, hbuf, out);
}